// Round 14
// baseline (236.103 us; speedup 1.0000x reference)
//
#include <hip/hip_runtime.h>

typedef unsigned short u16;
typedef __attribute__((ext_vector_type(8))) short short8;
typedef __attribute__((ext_vector_type(4))) unsigned short u16x4;
typedef __attribute__((ext_vector_type(4))) float f32x4;

#define N_TOKENS 32768
#define EMBED 512
#define NCLS 16
#define NBATCH 8
#define NHEAD 8
#define DHEAD 64

__device__ __forceinline__ u16 f2bf(float f) {
  unsigned u = __float_as_uint(f);
  u += 0x7fffu + ((u >> 16) & 1u);   // RNE
  return (u16)(u >> 16);
}

__device__ __forceinline__ void async16(const u16* g, u16* l) {
  __builtin_amdgcn_global_load_lds(
      (__attribute__((address_space(1))) const unsigned int*)(const void*)g,
      (__attribute__((address_space(3))) unsigned int*)(void*)l,
      16, 0, 0);
}

// ---------------- K/V projection v12: coalesced wave-per-row (r12, fast) ----------------
__global__ __launch_bounds__(256) void kvproj_kernel(
    const float* __restrict__ key, const float* __restrict__ val,
    const float* __restrict__ Wk, const float* __restrict__ bk,
    const float* __restrict__ Wv, const float* __restrict__ bv,
    float* __restrict__ kproj, float* __restrict__ vproj) {
  const int blk = blockIdx.x;           // isV(1) | b(3) | l(4) | fg(3)
  const bool isV = blk & 1;
  const int b = (blk >> 1) & 7;
  const int l = (blk >> 4) & 15;
  const int fg = blk >> 8;              // [0,8)
  const int wave = threadIdx.x >> 6;
  const int lane = threadIdx.x & 63;
  const int fbase = fg * 64 + wave * 16;   // wave owns 16 f-rows
  const float* x = (isV ? val : key) + ((size_t)l * NBATCH + b) * EMBED;
  const float* W = isV ? Wv : Wk;
  const float* bias = isV ? bv : bk;

  float4 x0 = *(const float4*)(x + lane * 8);
  float4 x1 = *(const float4*)(x + lane * 8 + 4);

#pragma unroll
  for (int grp = 0; grp < 4; grp++) {
    float acc[4];
#pragma unroll
    for (int j = 0; j < 4; j++) {
      const float* w = W + (size_t)(fbase + grp * 4 + j) * EMBED + lane * 8;
      float4 w0 = *(const float4*)w;
      float4 w1 = *(const float4*)(w + 4);
      acc[j] = x0.x * w0.x + x0.y * w0.y + x0.z * w0.z + x0.w * w0.w +
               x1.x * w1.x + x1.y * w1.y + x1.z * w1.z + x1.w * w1.w;
    }
#pragma unroll
    for (int j = 0; j < 4; j++) {
      acc[j] += __shfl_xor(acc[j], 1);
      acc[j] += __shfl_xor(acc[j], 2);
      acc[j] += __shfl_xor(acc[j], 4);
      acc[j] += __shfl_xor(acc[j], 8);
      acc[j] += __shfl_xor(acc[j], 16);
      acc[j] += __shfl_xor(acc[j], 32);
    }
#pragma unroll
    for (int j = 0; j < 4; j++) {
      if (lane == j) {                   // compile-time acc index (no scratch)
        const int f = fbase + grp * 4 + j;
        float v = acc[j] + bias[f];
        if (!isV) {
          kproj[((size_t)(b * EMBED + f)) * NCLS + l] = v;            // [b][h][d][l]
        } else {
          vproj[(size_t)b * 8192 + (size_t)(f >> 6) * 1024 + l * 64 + (f & 63)] = v;
        }
      }
    }
  }
}

// ---------------- merged build: Kq / WoV / sb (r6, passing) ----------------
__global__ __launch_bounds__(256) void build_all(
    const float* __restrict__ kproj, const float* __restrict__ vproj,
    const float* __restrict__ Wq, const float* __restrict__ bq,
    const float* __restrict__ Wo,
    u16* __restrict__ Kqb, u16* __restrict__ WoVb, float* __restrict__ sb) {
  const int blk = blockIdx.x;
  if (blk < 2048) {
    int t = blk * 256 + threadIdx.x;   // 8*128*512
    int e = t & 511;
    int hl = (t >> 9) & 127;
    int b = t >> 16;
    int h = hl >> 4, l = hl & 15;
    const float* kp = kproj + (size_t)b * 8192 + h * 1024 + l;
    const float* wq = Wq + (size_t)(h * 64) * 512 + e;
    float acc = 0.f;
#pragma unroll 16
    for (int d = 0; d < 64; d++) acc += kp[d * 16] * wq[d * 512];
    Kqb[t] = f2bf(acc);
  } else if (blk < 3072) {
    const int wave = threadIdx.x >> 6;
    const int lane = threadIdx.x & 63;
    const int wgid = (blk - 2048) * 4 + wave;   // [0,4096)
    const int b = wgid >> 9, f = wgid & 511;
    const int l = lane >> 2, c = lane & 3;
    const float* vp = vproj + (size_t)b * 8192 + l * 64 + c * 16;
    const float* wo = Wo + (size_t)f * 512 + c * 16;
#pragma unroll 2
    for (int h = 0; h < 8; h++) {
      const float* v = vp + h * 1024;
      const float* w = wo + h * 64;
      float4 v0 = *(const float4*)v,       w0 = *(const float4*)w;
      float4 v1 = *(const float4*)(v + 4), w1 = *(const float4*)(w + 4);
      float4 v2 = *(const float4*)(v + 8), w2 = *(const float4*)(w + 8);
      float4 v3 = *(const float4*)(v + 12), w3 = *(const float4*)(w + 12);
      float acc = v0.x * w0.x + v0.y * w0.y + v0.z * w0.z + v0.w * w0.w +
                  v1.x * w1.x + v1.y * w1.y + v1.z * w1.z + v1.w * w1.w +
                  v2.x * w2.x + v2.y * w2.y + v2.z * w2.z + v2.w * w2.w +
                  v3.x * w3.x + v3.y * w3.y + v3.z * w3.z + v3.w * w3.w;
      acc += __shfl_xor(acc, 1);
      acc += __shfl_xor(acc, 2);
      if (c == 0) WoVb[(size_t)b * 65536 + (size_t)f * 128 + h * 16 + l] = f2bf(acc);
    }
  } else {
    int t = (blk - 3072) * 256 + threadIdx.x;   // 1024
    int hl = t & 127, b = t >> 7;
    int h = hl >> 4, l = hl & 15;
    const float* kp = kproj + (size_t)b * 8192 + h * 1024 + l;
    const float* q = bq + h * 64;
    float acc = 0.f;
#pragma unroll
    for (int d = 0; d < 64; d++) acc += q[d] * kp[d * 16];
    sb[t] = acc;
  }
}

// ---------------- fused: scores GEMM + softmax + out GEMM ----------------
// v14 = r13 body on a register diet targeting the <=128 VGPR bucket (m69:
// waves/SIMD steps at 64/128/256) WITHOUT launch_bounds (3x proven to spill):
//  * BK back to 32 (r9 showed BK64 neutral) -> Bs 16KB, LDS 32KB total.
//  * phase-2 ni-split: acc2[4][2] (-32 regs); WoV request count unchanged,
//    only cheap paf LDS re-reads doubled.
//  * rowb loaded in the epilogue, not held across the kernel (-16 regs).
//  * softmax max-pass DROPPED: |v*0.125| <~17 -> exp <= 2.4e7, safe in fp32,
//    mathematically identical; halves the dependent-shfl chain.
// WRITE_SIZE canary: must stay exactly 65536 KB (any growth = spills).
__global__ __launch_bounds__(256) void fused_attn(
    const float* __restrict__ query, const u16* __restrict__ Kqb,
    const u16* __restrict__ WoVb, const float* __restrict__ sb,
    const float* __restrict__ bo, const int* __restrict__ bidx,
    float* __restrict__ out) {
  __shared__ __align__(16) u16 Bs[2][128 * 32];   // 16 KB: Kq k-slice, dbuf
  __shared__ __align__(16) u16 Ps[64 * 128];      // 16 KB: P, XOR-swizzled
  const int tid = threadIdx.x;
  const int lane = tid & 63;
  const int wave = tid >> 6;
  const int quad = lane >> 4;
  const int l16 = lane & 15;
  const int tileId = blockIdx.x & 511;    // slot in HIGH bit (XCD parity fix)
  const int slot = blockIdx.x >> 9;
  const int m0 = tileId * 64;
  const int bFirst = bidx[m0];
  const int bLast = bidx[m0 + 63];
  if (slot == 1 && bFirst == bLast) return;   // uniform exit, before any barrier
  const int b0 = (slot == 0) ? bFirst : bFirst + 1;
  const int b1 = (slot == 0) ? bFirst : bLast;

  // staging coords (BK=32): 512 chunks of 16B per 8KB slice; thread owns
  // chunks tid, tid+256. chunk c -> row=c>>2, phys=c&3; source pre-swizzled.
  const int r0 = tid >> 2, r1 = r0 + 64;
  const int lg0 = (tid & 3) ^ ((r0 >> 1) & 3);
  const int lg1 = (tid & 3) ^ ((r1 >> 1) & 3);
  const size_t boff0 = (size_t)r0 * 512 + lg0 * 8;
  const size_t boff1 = (size_t)r1 * 512 + lg1 * 8;

  // phase-1 A pointer: wave-exclusive row (fp32), quad picks 8-elem sub-slice
  const float* pA = query + (size_t)(m0 + wave * 16 + l16) * 512 + quad * 8;

  for (int bb = b0; bb <= b1; bb++) {
    const u16* Bq = Kqb + (size_t)bb * 65536;

    // prologue: stage k-slice 0 into buf 0; load A slice 0 (fp32)
    async16(Bq + boff0, &Bs[0][tid * 8]);
    async16(Bq + boff1, &Bs[0][tid * 8 + 2048]);
    float4 a0c = *(const float4*)(pA);
    float4 a1c = *(const float4*)(pA + 4);

    f32x4 acc1[8];
#pragma unroll
    for (int j = 0; j < 8; j++) acc1[j] = (f32x4){0.f, 0.f, 0.f, 0.f};

    for (int t = 0; t < 16; t++) {
      __syncthreads();                     // drains vmcnt -> buf[t&1] + A(t) ready
      const int cur = t & 1;
      if (t < 15) {                        // stage next k-slice; overlaps MFMA below
        const int ko = (t + 1) * 32;
        async16(Bq + boff0 + ko, &Bs[cur ^ 1][tid * 8]);
        async16(Bq + boff1 + ko, &Bs[cur ^ 1][tid * 8 + 2048]);
      }
      float4 a0 = a0c, a1 = a1c;
      if (t < 15) {                        // prefetch A(t+1)
        a0c = *(const float4*)(pA + (t + 1) * 32);
        a1c = *(const float4*)(pA + (t + 1) * 32 + 4);
      }
      short8 af;
      af[0] = (short)f2bf(a0.x); af[1] = (short)f2bf(a0.y);
      af[2] = (short)f2bf(a0.z); af[3] = (short)f2bf(a0.w);
      af[4] = (short)f2bf(a1.x); af[5] = (short)f2bf(a1.y);
      af[6] = (short)f2bf(a1.z); af[7] = (short)f2bf(a1.w);
      __builtin_amdgcn_s_setprio(1);
#pragma unroll
      for (int ni = 0; ni < 8; ni++) {
        const int rw = ni * 16 + l16;
        short8 bfr = *(const short8*)&Bs[cur][rw * 32 + ((quad ^ ((rw >> 1) & 3)) << 3)];
        acc1[ni] = __builtin_amdgcn_mfma_f32_16x16x32_bf16(af, bfr, acc1[ni], 0, 0, 0);
      }
      __builtin_amdgcn_s_setprio(0);
    }

    // ---- softmax (no max-pass; scores bounded), P -> LDS swizzled ----
    float sbv[8];
#pragma unroll
    for (int ni = 0; ni < 8; ni++) sbv[ni] = sb[bb * 128 + ni * 16 + l16];
#pragma unroll
    for (int r = 0; r < 4; r++) {
      const int row = wave * 16 + quad * 4 + r;   // wave-exclusive rows
#pragma unroll
      for (int ni = 0; ni < 8; ni++) {
        float v = acc1[ni][r] + sbv[ni];
        float ev = __expf(v * 0.125f);   // scale = D^-0.5
        float s = ev;
        s += __shfl_xor(s, 1);
        s += __shfl_xor(s, 2);
        s += __shfl_xor(s, 4);
        s += __shfl_xor(s, 8);
        const int col = ni * 16 + l16;
        Ps[row * 128 + (((col >> 3) ^ (row & 7)) << 3) + (col & 7)] = f2bf(ev / s);
      }
    }
    __syncthreads();   // all P stripes visible

    // ---- phase 2: out[64,512] = P x WoV[bb]^T; wave owns 128 f-cols ----
    const u16* Wv = WoVb + (size_t)bb * 65536;
#pragma unroll
    for (int h2 = 0; h2 < 2; h2++) {
#pragma unroll
      for (int nh = 0; nh < 2; nh++) {
        const int f0 = wave * 128 + h2 * 64 + nh * 32;
        f32x4 acc2[4][2];
#pragma unroll
        for (int i = 0; i < 4; i++)
#pragma unroll
          for (int j = 0; j < 2; j++) acc2[i][j] = (f32x4){0.f, 0.f, 0.f, 0.f};
#pragma unroll
        for (int kk = 0; kk < 4; kk++) {
          short8 paf[4], bf2[2];
#pragma unroll
          for (int mi = 0; mi < 4; mi++) {
            const int row = mi * 16 + l16;
            paf[mi] = *(const short8*)&Ps[row * 128 + (((kk * 4 + quad) ^ (row & 7)) << 3)];
          }
#pragma unroll
          for (int nj = 0; nj < 2; nj++) {
            const int fr = f0 + nj * 16 + l16;
            bf2[nj] = *(const short8*)(Wv + (size_t)fr * 128 + kk * 32 + quad * 8);
          }
          __builtin_amdgcn_s_setprio(1);
#pragma unroll
          for (int mi = 0; mi < 4; mi++)
#pragma unroll
            for (int nj = 0; nj < 2; nj++)
              acc2[mi][nj] = __builtin_amdgcn_mfma_f32_16x16x32_bf16(paf[mi], bf2[nj], acc2[mi][nj], 0, 0, 0);
          __builtin_amdgcn_s_setprio(0);
        }
        float bov[2];
#pragma unroll
        for (int nj = 0; nj < 2; nj++) bov[nj] = bo[f0 + nj * 16 + l16];
#pragma unroll
        for (int mi = 0; mi < 4; mi++)
#pragma unroll
          for (int r = 0; r < 4; r++) {
            const int rb = bidx[m0 + mi * 16 + quad * 4 + r];   // epilogue-local (L1-hot)
            if (rb == bb) {
              const size_t row = m0 + mi * 16 + quad * 4 + r;
#pragma unroll
              for (int nj = 0; nj < 2; nj++)
                out[row * 512 + f0 + nj * 16 + l16] = acc2[mi][nj][r] + bov[nj];
            }
          }
      }
    }
    __syncthreads();   // Ps/Bs safe to overwrite next bb
  }
}

extern "C" void kernel_launch(void* const* d_in, const int* in_sizes, int n_in,
                              void* d_out, int out_size, void* d_ws, size_t ws_size,
                              hipStream_t stream) {
  const float* query = (const float*)d_in[0];
  const float* keyt = (const float*)d_in[1];
  const float* valt = (const float*)d_in[2];
  const int* bidx = (const int*)d_in[3];
  // d_in[4] = batch_size (scalar, fixed = 8)
  const float* Wq = (const float*)d_in[5];
  const float* bq = (const float*)d_in[6];
  const float* Wk = (const float*)d_in[7];
  const float* bk = (const float*)d_in[8];
  const float* Wv = (const float*)d_in[9];
  const float* bv = (const float*)d_in[10];
  const float* Wo = (const float*)d_in[11];
  const float* bo = (const float*)d_in[12];
  float* out = (float*)d_out;

  // workspace layout (bytes)
  unsigned char* w = (unsigned char*)d_ws;
  float* kproj = (float*)(w + 41943040ull);   //    262,144: [B,H,D,L]
  float* vproj = (float*)(w + 42205184ull);   //    262,144: [B,H,L,D]
  u16* Kqb = (u16*)(w + 42467328ull);         //  1,048,576: [B,128,512] bf16
  u16* WoVb = (u16*)(w + 43515904ull);        //  1,048,576: [B,512,128] bf16
  float* sb = (float*)(w + 44564480ull);      //      4,096: [B,128]

  // 1) K/V projections (coalesced wave-per-row, 2048 blocks)
  kvproj_kernel<<<2048, 256, 0, stream>>>(keyt, valt, Wk, bk, Wv, bv, kproj, vproj);

  // 2) fold Wq through k, Wo through v, and sb — one launch
  build_all<<<3076, 256, 0, stream>>>(kproj, vproj, Wq, bq, Wo, Kqb, WoVb, sb);

  // 3) fused: fp32 query -> scores -> softmax -> out (slot in HIGH bit)
  fused_attn<<<N_TOKENS / 64 * 2, 256, 0, stream>>>(query, Kqb, WoVb, sb, bo, bidx, out);
}

// Round 15
// 222.728 us; speedup vs baseline: 1.0601x; 1.0601x over previous
//
#include <hip/hip_runtime.h>

typedef unsigned short u16;
typedef __attribute__((ext_vector_type(8))) short short8;
typedef __attribute__((ext_vector_type(4))) unsigned short u16x4;
typedef __attribute__((ext_vector_type(4))) float f32x4;

#define N_TOKENS 32768
#define EMBED 512
#define NCLS 16
#define NBATCH 8
#define NHEAD 8
#define DHEAD 64

__device__ __forceinline__ u16 f2bf(float f) {
  unsigned u = __float_as_uint(f);
  u += 0x7fffu + ((u >> 16) & 1u);   // RNE
  return (u16)(u >> 16);
}

__device__ __forceinline__ void async16(const u16* g, u16* l) {
  __builtin_amdgcn_global_load_lds(
      (__attribute__((address_space(1))) const unsigned int*)(const void*)g,
      (__attribute__((address_space(3))) unsigned int*)(void*)l,
      16, 0, 0);
}

// ---------------- K/V projection v12: coalesced wave-per-row (r12, fast) ----------------
__global__ __launch_bounds__(256) void kvproj_kernel(
    const float* __restrict__ key, const float* __restrict__ val,
    const float* __restrict__ Wk, const float* __restrict__ bk,
    const float* __restrict__ Wv, const float* __restrict__ bv,
    float* __restrict__ kproj, float* __restrict__ vproj) {
  const int blk = blockIdx.x;           // isV(1) | b(3) | l(4) | fg(3)
  const bool isV = blk & 1;
  const int b = (blk >> 1) & 7;
  const int l = (blk >> 4) & 15;
  const int fg = blk >> 8;              // [0,8)
  const int wave = threadIdx.x >> 6;
  const int lane = threadIdx.x & 63;
  const int fbase = fg * 64 + wave * 16;   // wave owns 16 f-rows
  const float* x = (isV ? val : key) + ((size_t)l * NBATCH + b) * EMBED;
  const float* W = isV ? Wv : Wk;
  const float* bias = isV ? bv : bk;

  float4 x0 = *(const float4*)(x + lane * 8);
  float4 x1 = *(const float4*)(x + lane * 8 + 4);

#pragma unroll
  for (int grp = 0; grp < 4; grp++) {
    float acc[4];
#pragma unroll
    for (int j = 0; j < 4; j++) {
      const float* w = W + (size_t)(fbase + grp * 4 + j) * EMBED + lane * 8;
      float4 w0 = *(const float4*)w;
      float4 w1 = *(const float4*)(w + 4);
      acc[j] = x0.x * w0.x + x0.y * w0.y + x0.z * w0.z + x0.w * w0.w +
               x1.x * w1.x + x1.y * w1.y + x1.z * w1.z + x1.w * w1.w;
    }
#pragma unroll
    for (int j = 0; j < 4; j++) {
      acc[j] += __shfl_xor(acc[j], 1);
      acc[j] += __shfl_xor(acc[j], 2);
      acc[j] += __shfl_xor(acc[j], 4);
      acc[j] += __shfl_xor(acc[j], 8);
      acc[j] += __shfl_xor(acc[j], 16);
      acc[j] += __shfl_xor(acc[j], 32);
    }
#pragma unroll
    for (int j = 0; j < 4; j++) {
      if (lane == j) {                   // compile-time acc index (no scratch)
        const int f = fbase + grp * 4 + j;
        float v = acc[j] + bias[f];
        if (!isV) {
          kproj[((size_t)(b * EMBED + f)) * NCLS + l] = v;            // [b][h][d][l]
        } else {
          vproj[(size_t)b * 8192 + (size_t)(f >> 6) * 1024 + l * 64 + (f & 63)] = v;
        }
      }
    }
  }
}

// ---------------- merged build: Kq / WoV / sb (r6, passing) ----------------
__global__ __launch_bounds__(256) void build_all(
    const float* __restrict__ kproj, const float* __restrict__ vproj,
    const float* __restrict__ Wq, const float* __restrict__ bq,
    const float* __restrict__ Wo,
    u16* __restrict__ Kqb, u16* __restrict__ WoVb, float* __restrict__ sb) {
  const int blk = blockIdx.x;
  if (blk < 2048) {
    int t = blk * 256 + threadIdx.x;   // 8*128*512
    int e = t & 511;
    int hl = (t >> 9) & 127;
    int b = t >> 16;
    int h = hl >> 4, l = hl & 15;
    const float* kp = kproj + (size_t)b * 8192 + h * 1024 + l;
    const float* wq = Wq + (size_t)(h * 64) * 512 + e;
    float acc = 0.f;
#pragma unroll 16
    for (int d = 0; d < 64; d++) acc += kp[d * 16] * wq[d * 512];
    Kqb[t] = f2bf(acc);
  } else if (blk < 3072) {
    const int wave = threadIdx.x >> 6;
    const int lane = threadIdx.x & 63;
    const int wgid = (blk - 2048) * 4 + wave;   // [0,4096)
    const int b = wgid >> 9, f = wgid & 511;
    const int l = lane >> 2, c = lane & 3;
    const float* vp = vproj + (size_t)b * 8192 + l * 64 + c * 16;
    const float* wo = Wo + (size_t)f * 512 + c * 16;
#pragma unroll 2
    for (int h = 0; h < 8; h++) {
      const float* v = vp + h * 1024;
      const float* w = wo + h * 64;
      float4 v0 = *(const float4*)v,       w0 = *(const float4*)w;
      float4 v1 = *(const float4*)(v + 4), w1 = *(const float4*)(w + 4);
      float4 v2 = *(const float4*)(v + 8), w2 = *(const float4*)(w + 8);
      float4 v3 = *(const float4*)(v + 12), w3 = *(const float4*)(w + 12);
      float acc = v0.x * w0.x + v0.y * w0.y + v0.z * w0.z + v0.w * w0.w +
                  v1.x * w1.x + v1.y * w1.y + v1.z * w1.z + v1.w * w1.w +
                  v2.x * w2.x + v2.y * w2.y + v2.z * w2.z + v2.w * w2.w +
                  v3.x * w3.x + v3.y * w3.y + v3.z * w3.z + v3.w * w3.w;
      acc += __shfl_xor(acc, 1);
      acc += __shfl_xor(acc, 2);
      if (c == 0) WoVb[(size_t)b * 65536 + (size_t)f * 128 + h * 16 + l] = f2bf(acc);
    }
  } else {
    int t = (blk - 3072) * 256 + threadIdx.x;   // 1024
    int hl = t & 127, b = t >> 7;
    int h = hl >> 4, l = hl & 15;
    const float* kp = kproj + (size_t)b * 8192 + h * 1024 + l;
    const float* q = bq + h * 64;
    float acc = 0.f;
#pragma unroll
    for (int d = 0; d < 64; d++) acc += q[d] * kp[d * 16];
    sb[t] = acc;
  }
}

// ---------------- fused: scores GEMM + softmax + out GEMM ----------------
// v15: 32-token tiles, grid 2x1024 -> 4-6 blocks/CU co-resident (grid, not
// regs, capped TLP at 64-token tiles: 512 blocks = 2/CU max, and every
// schedule variant plateaued at 78-100us). LDS 24KB (Bs 16 + Ps 8).
// Phase 1: wave owns 16 rows x 64 cols (acc1[4]); 4 waves tile the 32x128 C.
// All machinery verbatim r13: BK32 staging+swizzle, max-softmax, uncapped
// regs (3x proven: caps => spills), slot in HIGH bit (XCD parity).
// WRITE_SIZE canary: must stay exactly 65536 KB.
__global__ __launch_bounds__(256) void fused_attn(
    const float* __restrict__ query, const u16* __restrict__ Kqb,
    const u16* __restrict__ WoVb, const float* __restrict__ sb,
    const float* __restrict__ bo, const int* __restrict__ bidx,
    float* __restrict__ out) {
  __shared__ __align__(16) u16 Bs[2][128 * 32];   // 16 KB: Kq k-slice, dbuf
  __shared__ __align__(16) u16 Ps[32 * 128];      // 8 KB: P, XOR-swizzled
  const int tid = threadIdx.x;
  const int lane = tid & 63;
  const int wave = tid >> 6;
  const int quad = lane >> 4;
  const int l16 = lane & 15;
  const int tileId = blockIdx.x & 1023;   // slot in HIGH bit (XCD parity fix)
  const int slot = blockIdx.x >> 10;
  const int m0 = tileId * 32;
  const int bFirst = bidx[m0];
  const int bLast = bidx[m0 + 31];
  if (slot == 1 && bFirst == bLast) return;   // uniform exit, before any barrier
  const int b0 = (slot == 0) ? bFirst : bFirst + 1;
  const int b1 = (slot == 0) ? bFirst : bLast;

  // staging coords (BK=32): 512 chunks of 16B per 8KB slice; thread owns
  // chunks tid, tid+256. chunk c -> row=c>>2, phys=c&3; source pre-swizzled.
  const int r0 = tid >> 2, r1 = r0 + 64;
  const int lg0 = (tid & 3) ^ ((r0 >> 1) & 3);
  const int lg1 = (tid & 3) ^ ((r1 >> 1) & 3);
  const size_t boff0 = (size_t)r0 * 512 + lg0 * 8;
  const size_t boff1 = (size_t)r1 * 512 + lg1 * 8;

  const int wr = (wave & 1) * 16;    // phase-1 row base (within tile)
  const int wcb = (wave >> 1) * 64;  // phase-1 col base (hl)

  // phase-1 A pointer: wave-row, quad picks 8-elem k-slice (fp32)
  const float* pA = query + (size_t)(m0 + wr + l16) * 512 + quad * 8;

  for (int bb = b0; bb <= b1; bb++) {
    const u16* Bq = Kqb + (size_t)bb * 65536;

    // prologue: stage k-slice 0 into buf 0; load A slice 0 (fp32)
    async16(Bq + boff0, &Bs[0][tid * 8]);
    async16(Bq + boff1, &Bs[0][tid * 8 + 2048]);
    float4 a0c = *(const float4*)(pA);
    float4 a1c = *(const float4*)(pA + 4);

    f32x4 acc1[4];
#pragma unroll
    for (int j = 0; j < 4; j++) acc1[j] = (f32x4){0.f, 0.f, 0.f, 0.f};

    for (int t = 0; t < 16; t++) {
      __syncthreads();                     // drains vmcnt -> buf[t&1] + A(t) ready
      const int cur = t & 1;
      if (t < 15) {                        // stage next k-slice; overlaps MFMA below
        const int ko = (t + 1) * 32;
        async16(Bq + boff0 + ko, &Bs[cur ^ 1][tid * 8]);
        async16(Bq + boff1 + ko, &Bs[cur ^ 1][tid * 8 + 2048]);
      }
      float4 a0 = a0c, a1 = a1c;
      if (t < 15) {                        // prefetch A(t+1)
        a0c = *(const float4*)(pA + (t + 1) * 32);
        a1c = *(const float4*)(pA + (t + 1) * 32 + 4);
      }
      short8 af;
      af[0] = (short)f2bf(a0.x); af[1] = (short)f2bf(a0.y);
      af[2] = (short)f2bf(a0.z); af[3] = (short)f2bf(a0.w);
      af[4] = (short)f2bf(a1.x); af[5] = (short)f2bf(a1.y);
      af[6] = (short)f2bf(a1.z); af[7] = (short)f2bf(a1.w);
      __builtin_amdgcn_s_setprio(1);
#pragma unroll
      for (int ni = 0; ni < 4; ni++) {
        const int rw = wcb + ni * 16 + l16;
        short8 bfr = *(const short8*)&Bs[cur][rw * 32 + ((quad ^ ((rw >> 1) & 3)) << 3)];
        acc1[ni] = __builtin_amdgcn_mfma_f32_16x16x32_bf16(af, bfr, acc1[ni], 0, 0, 0);
      }
      __builtin_amdgcn_s_setprio(0);
    }

    // ---- softmax over each head's 16 l-cols (16-lane shfl), P -> LDS ----
    float sbv[4];
#pragma unroll
    for (int ni = 0; ni < 4; ni++) sbv[ni] = sb[bb * 128 + wcb + ni * 16 + l16];
#pragma unroll
    for (int r = 0; r < 4; r++) {
      const int row = wr + quad * 4 + r;   // 0..31
#pragma unroll
      for (int ni = 0; ni < 4; ni++) {
        float v = acc1[ni][r] + sbv[ni];
        float mx = v;
        mx = fmaxf(mx, __shfl_xor(mx, 1));
        mx = fmaxf(mx, __shfl_xor(mx, 2));
        mx = fmaxf(mx, __shfl_xor(mx, 4));
        mx = fmaxf(mx, __shfl_xor(mx, 8));
        float ev = __expf((v - mx) * 0.125f);   // scale = D^-0.5
        float s = ev;
        s += __shfl_xor(s, 1);
        s += __shfl_xor(s, 2);
        s += __shfl_xor(s, 4);
        s += __shfl_xor(s, 8);
        const int col = wcb + ni * 16 + l16;
        Ps[row * 128 + (((col >> 3) ^ (row & 7)) << 3) + (col & 7)] = f2bf(ev / s);
      }
    }
    __syncthreads();   // all P stripes visible

    // ---- phase 2: out[32,512] = P x WoV[bb]^T; wave owns 128 f-cols ----
    const u16* Wv = WoVb + (size_t)bb * 65536;
#pragma unroll
    for (int h2 = 0; h2 < 2; h2++) {
      const int f0 = wave * 128 + h2 * 64;
      f32x4 acc2[2][4];
#pragma unroll
      for (int i = 0; i < 2; i++)
#pragma unroll
        for (int j = 0; j < 4; j++) acc2[i][j] = (f32x4){0.f, 0.f, 0.f, 0.f};
#pragma unroll
      for (int kk = 0; kk < 4; kk++) {
        short8 paf[2], bf2[4];
#pragma unroll
        for (int mi = 0; mi < 2; mi++) {
          const int row = mi * 16 + l16;
          paf[mi] = *(const short8*)&Ps[row * 128 + (((kk * 4 + quad) ^ (row & 7)) << 3)];
        }
#pragma unroll
        for (int ni = 0; ni < 4; ni++) {
          const int fr = f0 + ni * 16 + l16;
          bf2[ni] = *(const short8*)(Wv + (size_t)fr * 128 + kk * 32 + quad * 8);
        }
        __builtin_amdgcn_s_setprio(1);
#pragma unroll
        for (int mi = 0; mi < 2; mi++)
#pragma unroll
          for (int ni = 0; ni < 4; ni++)
            acc2[mi][ni] = __builtin_amdgcn_mfma_f32_16x16x32_bf16(paf[mi], bf2[ni], acc2[mi][ni], 0, 0, 0);
        __builtin_amdgcn_s_setprio(0);
      }
      float bov[4];
#pragma unroll
      for (int ni = 0; ni < 4; ni++) bov[ni] = bo[f0 + ni * 16 + l16];
#pragma unroll
      for (int mi = 0; mi < 2; mi++)
#pragma unroll
        for (int r = 0; r < 4; r++) {
          const int rb = bidx[m0 + mi * 16 + quad * 4 + r];   // epilogue-local (L1-hot)
          if (rb == bb) {
            const size_t row = m0 + mi * 16 + quad * 4 + r;
#pragma unroll
            for (int ni = 0; ni < 4; ni++)
              out[row * 512 + f0 + ni * 16 + l16] = acc2[mi][ni][r] + bov[ni];
          }
        }
    }
    __syncthreads();   // Ps/Bs safe to overwrite next bb
  }
}

extern "C" void kernel_launch(void* const* d_in, const int* in_sizes, int n_in,
                              void* d_out, int out_size, void* d_ws, size_t ws_size,
                              hipStream_t stream) {
  const float* query = (const float*)d_in[0];
  const float* keyt = (const float*)d_in[1];
  const float* valt = (const float*)d_in[2];
  const int* bidx = (const int*)d_in[3];
  // d_in[4] = batch_size (scalar, fixed = 8)
  const float* Wq = (const float*)d_in[5];
  const float* bq = (const float*)d_in[6];
  const float* Wk = (const float*)d_in[7];
  const float* bk = (const float*)d_in[8];
  const float* Wv = (const float*)d_in[9];
  const float* bv = (const float*)d_in[10];
  const float* Wo = (const float*)d_in[11];
  const float* bo = (const float*)d_in[12];
  float* out = (float*)d_out;

  // workspace layout (bytes)
  unsigned char* w = (unsigned char*)d_ws;
  float* kproj = (float*)(w + 41943040ull);   //    262,144: [B,H,D,L]
  float* vproj = (float*)(w + 42205184ull);   //    262,144: [B,H,L,D]
  u16* Kqb = (u16*)(w + 42467328ull);         //  1,048,576: [B,128,512] bf16
  u16* WoVb = (u16*)(w + 43515904ull);        //  1,048,576: [B,512,128] bf16
  float* sb = (float*)(w + 44564480ull);      //      4,096: [B,128]

  // 1) K/V projections (coalesced wave-per-row, 2048 blocks)
  kvproj_kernel<<<2048, 256, 0, stream>>>(keyt, valt, Wk, bk, Wv, bv, kproj, vproj);

  // 2) fold Wq through k, Wo through v, and sb — one launch
  build_all<<<3076, 256, 0, stream>>>(kproj, vproj, Wq, bq, Wo, Kqb, WoVb, sb);

  // 3) fused: fp32 query -> scores -> softmax -> out (32-token tiles)
  fused_attn<<<N_TOKENS / 32 * 2, 256, 0, stream>>>(query, Kqb, WoVb, sb, bo, bidx, out);
}